// Round 1
// baseline (506.017 us; speedup 1.0000x reference)
//
#include <hip/hip_runtime.h>

#define NB 16
#define NCH 64
#define NT 2048
#define TI 64
#define TJ 64
#define LDSP 68   // padded row stride (floats): 16B-aligned rows, bank-staggered

// ---- kernel 1: X[b,t] = sum_c x[b,c,t] ----
__global__ __launch_bounds__(256)
void colsum_k(const float* __restrict__ x, float* __restrict__ Xs) {
    int idx = blockIdx.x * 256 + threadIdx.x;          // over NB*NT
    int b = idx >> 11;                                 // /2048
    int t = idx & (NT - 1);
    const float* xp = x + (size_t)b * NCH * NT + t;
    float s = 0.f;
    #pragma unroll
    for (int c = 0; c < NCH; ++c) s += xp[(size_t)c * NT];
    Xs[idx] = s;
}

// ---- kernel 2: fused energy -> minmax-norm -> softmax -> mixed -> out ----
__global__ __launch_bounds__(256)
void attn_k(const float* __restrict__ x,
            const float* __restrict__ w1, const float* __restrict__ b1,
            const float* __restrict__ w2, const float* __restrict__ b2,
            const float* __restrict__ gammap,
            const float* __restrict__ Xs,
            float* __restrict__ out) {
    __shared__ float xi[NCH][LDSP];      // x[b, :, i-tile]
    __shared__ float xj[NCH][LDSP];      // x[b, :, j-chunk]
    __shared__ float P [TI ][LDSP];      // exp tile
    __shared__ float red[TI][16];
    __shared__ float rowMin[TI], rowMax[TI], rowSum[TI];

    const int b  = blockIdx.y;
    const int i0 = blockIdx.x * TI;
    const int tid = threadIdx.x;
    const int ti = tid >> 4;     // 0..15
    const int tj = tid & 15;     // 0..15

    // rank-1 factorization scalars
    float s11 = 0.f, s1b2 = 0.f, s2b1 = 0.f, sbb = 0.f;
    #pragma unroll
    for (int f = 0; f < 8; ++f) {
        s11  += w1[f] * w2[f];
        s1b2 += w1[f] * b2[f];
        s2b1 += b1[f] * w2[f];
        sbb  += b1[f] * b2[f];
    }
    const float c0 = (float)NCH * sbb;
    const float g  = gammap[0];

    const float* xb = x + (size_t)b * NCH * NT;

    // stage xi (64ch x 64 rows)
    for (int idx = tid; idx < NCH * TI; idx += 256) {
        int c = idx >> 6, ii = idx & 63;
        xi[c][ii] = xb[(size_t)c * NT + i0 + ii];
    }

    float XiV[4];
    #pragma unroll
    for (int m = 0; m < 4; ++m) XiV[m] = Xs[b * NT + i0 + ti * 4 + m];

    float rmin[4], rmax[4];
    #pragma unroll
    for (int m = 0; m < 4; ++m) { rmin[m] = 3.0e38f; rmax[m] = -3.0e38f; }

    // ---------- pass 1: row min/max ----------
    for (int j0 = 0; j0 < NT; j0 += TJ) {
        __syncthreads();
        for (int idx = tid; idx < NCH * TJ; idx += 256) {
            int c = idx >> 6, jj = idx & 63;
            xj[c][jj] = xb[(size_t)c * NT + j0 + jj];
        }
        __syncthreads();
        float acc[4][4] = {};
        #pragma unroll 8
        for (int k = 0; k < NCH; ++k) {
            float4 av = *reinterpret_cast<const float4*>(&xi[k][ti * 4]);
            float4 bv = *reinterpret_cast<const float4*>(&xj[k][tj * 4]);
            float a[4]  = {av.x, av.y, av.z, av.w};
            float bb[4] = {bv.x, bv.y, bv.z, bv.w};
            #pragma unroll
            for (int m = 0; m < 4; ++m)
                #pragma unroll
                for (int n = 0; n < 4; ++n)
                    acc[m][n] = fmaf(a[m], bb[n], acc[m][n]);
        }
        float XjV[4];
        #pragma unroll
        for (int n = 0; n < 4; ++n) XjV[n] = Xs[b * NT + j0 + tj * 4 + n];
        #pragma unroll
        for (int m = 0; m < 4; ++m)
            #pragma unroll
            for (int n = 0; n < 4; ++n) {
                float e = s11 * acc[m][n] + s1b2 * XiV[m] + s2b1 * XjV[n] + c0;
                rmin[m] = fminf(rmin[m], e);
                rmax[m] = fmaxf(rmax[m], e);
            }
    }

    // reduce min/max across the 16 tj-threads per row
    #pragma unroll
    for (int m = 0; m < 4; ++m) red[ti * 4 + m][tj] = rmin[m];
    __syncthreads();
    if (tid < TI) {
        float v = red[tid][0];
        for (int u = 1; u < 16; ++u) v = fminf(v, red[tid][u]);
        rowMin[tid] = v;
    }
    __syncthreads();
    #pragma unroll
    for (int m = 0; m < 4; ++m) red[ti * 4 + m][tj] = rmax[m];
    __syncthreads();
    if (tid < TI) {
        float v = red[tid][0];
        for (int u = 1; u < 16; ++u) v = fmaxf(v, red[tid][u]);
        rowMax[tid] = v;
    }
    __syncthreads();

    float mn[4], inv[4];
    #pragma unroll
    for (int m = 0; m < 4; ++m) {
        mn[m]  = rowMin[ti * 4 + m];
        inv[m] = 1.f / (rowMax[ti * 4 + m] - mn[m] + 1e-8f);
    }

    float psum[4] = {0.f, 0.f, 0.f, 0.f};
    float macc[4][4] = {};   // [m]=channel c=ti*4+m, [n]=row i=tj*4+n

    // ---------- pass 2: exp + P-GEMM ----------
    for (int j0 = 0; j0 < NT; j0 += TJ) {
        __syncthreads();
        for (int idx = tid; idx < NCH * TJ; idx += 256) {
            int c = idx >> 6, jj = idx & 63;
            xj[c][jj] = xb[(size_t)c * NT + j0 + jj];
        }
        __syncthreads();
        float acc[4][4] = {};
        #pragma unroll 8
        for (int k = 0; k < NCH; ++k) {
            float4 av = *reinterpret_cast<const float4*>(&xi[k][ti * 4]);
            float4 bv = *reinterpret_cast<const float4*>(&xj[k][tj * 4]);
            float a[4]  = {av.x, av.y, av.z, av.w};
            float bb[4] = {bv.x, bv.y, bv.z, bv.w};
            #pragma unroll
            for (int m = 0; m < 4; ++m)
                #pragma unroll
                for (int n = 0; n < 4; ++n)
                    acc[m][n] = fmaf(a[m], bb[n], acc[m][n]);
        }
        float XjV[4];
        #pragma unroll
        for (int n = 0; n < 4; ++n) XjV[n] = Xs[b * NT + j0 + tj * 4 + n];
        #pragma unroll
        for (int m = 0; m < 4; ++m) {
            float p[4];
            #pragma unroll
            for (int n = 0; n < 4; ++n) {
                float e = s11 * acc[m][n] + s1b2 * XiV[m] + s2b1 * XjV[n] + c0;
                p[n] = __expf((e - mn[m]) * inv[m]);
                psum[m] += p[n];
            }
            *reinterpret_cast<float4*>(&P[ti * 4 + m][tj * 4]) =
                make_float4(p[0], p[1], p[2], p[3]);
        }
        __syncthreads();
        // mini-GEMM: macc[c, i] += sum_jj xj[c][jj] * P[i][jj]
        #pragma unroll 4
        for (int jj = 0; jj < TJ; jj += 4) {
            float4 xv[4], pv[4];
            #pragma unroll
            for (int m = 0; m < 4; ++m)
                xv[m] = *reinterpret_cast<const float4*>(&xj[ti * 4 + m][jj]);
            #pragma unroll
            for (int n = 0; n < 4; ++n)
                pv[n] = *reinterpret_cast<const float4*>(&P[tj * 4 + n][jj]);
            #pragma unroll
            for (int m = 0; m < 4; ++m)
                #pragma unroll
                for (int n = 0; n < 4; ++n) {
                    macc[m][n] = fmaf(xv[m].x, pv[n].x, macc[m][n]);
                    macc[m][n] = fmaf(xv[m].y, pv[n].y, macc[m][n]);
                    macc[m][n] = fmaf(xv[m].z, pv[n].z, macc[m][n]);
                    macc[m][n] = fmaf(xv[m].w, pv[n].w, macc[m][n]);
                }
        }
    }

    // reduce row sums
    #pragma unroll
    for (int m = 0; m < 4; ++m) red[ti * 4 + m][tj] = psum[m];
    __syncthreads();
    if (tid < TI) {
        float v = 0.f;
        for (int u = 0; u < 16; ++u) v += red[tid][u];
        rowSum[tid] = v;
    }
    __syncthreads();

    // out[b,c,i] = gamma * macc[c,i]/rowSum[i] + x[b,c,i]
    #pragma unroll
    for (int m = 0; m < 4; ++m) {
        int c = ti * 4 + m;
        #pragma unroll
        for (int n = 0; n < 4; ++n) {
            int i = i0 + tj * 4 + n;
            size_t off = (size_t)(b * NCH + c) * NT + i;
            out[off] = g * macc[m][n] / rowSum[tj * 4 + n] + xb[(size_t)c * NT + i];
        }
    }
}

extern "C" void kernel_launch(void* const* d_in, const int* in_sizes, int n_in,
                              void* d_out, int out_size, void* d_ws, size_t ws_size,
                              hipStream_t stream) {
    const float* x     = (const float*)d_in[0];
    const float* w1    = (const float*)d_in[1];
    const float* b1    = (const float*)d_in[2];
    const float* w2    = (const float*)d_in[3];
    const float* b2    = (const float*)d_in[4];
    const float* gamma = (const float*)d_in[5];
    float* out = (float*)d_out;
    float* Xs  = (float*)d_ws;   // NB*NT floats = 128 KB

    hipLaunchKernelGGL(colsum_k, dim3(NB * NT / 256), dim3(256), 0, stream, x, Xs);
    hipLaunchKernelGGL(attn_k, dim3(NT / TI, NB), dim3(256), 0, stream,
                       x, w1, b1, w2, b2, gamma, Xs, out);
}

// Round 2
// 111.094 us; speedup vs baseline: 4.5548x; 4.5548x over previous
//
#include <hip/hip_runtime.h>

#define NB 16
#define NCH 64
#define NT 2048
#define TI 64
#define TJ 64
#define STR 72   // bf16 LDS row stride: 144 B rows -> bank step 4, conflict-free b128 frags

typedef __attribute__((ext_vector_type(8))) short bf8;   // 8 bf16 in 4 VGPRs
typedef __attribute__((ext_vector_type(4))) float f4;    // MFMA accumulator

static __device__ __forceinline__ short f2b(float f) {
    // round-to-nearest-even fp32 -> bf16 (finite inputs)
    unsigned u = __float_as_uint(f);
    u += 0x7fffu + ((u >> 16) & 1u);
    return (short)(u >> 16);
}

// ---- prep: xT_bf[b][t][c] = bf16(x[b][c][t]); Xs[b][t] = sum_c x[b][c][t] ----
__global__ __launch_bounds__(256)
void prep_k(const float* __restrict__ x, float* __restrict__ Xs, short* __restrict__ xT) {
    __shared__ float T[NCH][65];
    const int b = blockIdx.y, t0 = blockIdx.x * 64;
    const int tid = threadIdx.x;
    const float* xb = x + (size_t)b * NCH * NT;

    const int tt = (tid & 15) * 4;
    #pragma unroll
    for (int co = 0; co < 4; ++co) {
        int c = co * 16 + (tid >> 4);
        float4 v = *reinterpret_cast<const float4*>(&xb[(size_t)c * NT + t0 + tt]);
        T[c][tt] = v.x; T[c][tt + 1] = v.y; T[c][tt + 2] = v.z; T[c][tt + 3] = v.w;
    }
    __syncthreads();
    if (tid < 64) {
        float s = 0.f;
        #pragma unroll
        for (int c = 0; c < NCH; ++c) s += T[c][tid];
        Xs[b * NT + t0 + tid] = s;
    }
    const int row = tid >> 2, cs = (tid & 3) * 16;
    bf8 v0, v1;
    #pragma unroll
    for (int u = 0; u < 8; ++u) v0[u] = f2b(T[cs + u][row]);
    #pragma unroll
    for (int u = 0; u < 8; ++u) v1[u] = f2b(T[cs + 8 + u][row]);
    short* dst = xT + ((size_t)b * NT + t0 + row) * NCH + cs;
    *reinterpret_cast<bf8*>(dst) = v0;
    *reinterpret_cast<bf8*>(dst + 8) = v1;
}

// ---- fused: energy(MFMA Gram) -> minmax -> softmax -> mixed(MFMA) -> out ----
__global__ __launch_bounds__(256)
void attn2_k(const float* __restrict__ x,
             const float* __restrict__ w1, const float* __restrict__ b1p,
             const float* __restrict__ w2, const float* __restrict__ b2p,
             const float* __restrict__ gp,
             const float* __restrict__ Xs, const short* __restrict__ xT,
             float* __restrict__ out) {
    __shared__ short xiT[TI][STR];   // xiT[i][c] = bf16 x[c][i0+i]
    __shared__ short xjT[TJ][STR];   // xjT[j][c]
    __shared__ short xjn[NCH][STR];  // xjn[c][j]  (natural, for mixed A)
    __shared__ short P[TI][STR];     // P[i][j] bf16
    __shared__ float XjL[TJ];
    __shared__ float rowSumL[TI];

    const int b  = blockIdx.y;
    const int i0 = blockIdx.x * TI;
    const int tid  = threadIdx.x;
    const int wid  = tid >> 6;
    const int lane = tid & 63;
    const int lq   = lane >> 4;   // k-group / acc-row-group
    const int ln   = lane & 15;   // m/n index within frag

    float s11 = 0.f, s1b2 = 0.f, s2b1 = 0.f, sbb = 0.f;
    #pragma unroll
    for (int f = 0; f < 8; ++f) {
        s11  += w1[f] * w2[f];
        s1b2 += w1[f] * b2p[f];
        s2b1 += b1p[f] * w2[f];
        sbb  += b1p[f] * b2p[f];
    }
    const float c0 = (float)NCH * sbb;
    const float g  = gp[0];

    const short* xTb = xT + (size_t)b * NT * NCH;
    const float* xb  = x + (size_t)b * NCH * NT;

    // stage xiT (once per block)
    {
        const int row = tid >> 2, cs = (tid & 3) * 16;
        const bf8* src = reinterpret_cast<const bf8*>(xTb + (size_t)(i0 + row) * NCH + cs);
        bf8* dst = reinterpret_cast<bf8*>(&xiT[row][cs]);
        dst[0] = src[0];
        dst[1] = src[1];
    }

    float XiV[4];
    #pragma unroll
    for (int r = 0; r < 4; ++r) XiV[r] = Xs[b * NT + i0 + wid * 16 + lq * 4 + r];

    float rmin[4], rmax[4];
    #pragma unroll
    for (int r = 0; r < 4; ++r) { rmin[r] = 3.0e38f; rmax[r] = -3.0e38f; }

    // ---------- pass 1: row min/max ----------
    for (int j0 = 0; j0 < NT; j0 += TJ) {
        __syncthreads();
        {
            const int row = tid >> 2, cs = (tid & 3) * 16;
            const bf8* src = reinterpret_cast<const bf8*>(xTb + (size_t)(j0 + row) * NCH + cs);
            bf8* dst = reinterpret_cast<bf8*>(&xjT[row][cs]);
            dst[0] = src[0];
            dst[1] = src[1];
        }
        if (tid < 16)
            reinterpret_cast<float4*>(XjL)[tid] =
                reinterpret_cast<const float4*>(Xs + b * NT + j0)[tid];
        __syncthreads();

        bf8 a0 = *reinterpret_cast<const bf8*>(&xiT[wid * 16 + ln][lq * 8]);
        bf8 a1 = *reinterpret_cast<const bf8*>(&xiT[wid * 16 + ln][32 + lq * 8]);
        #pragma unroll
        for (int nb = 0; nb < 4; ++nb) {
            bf8 bb0 = *reinterpret_cast<const bf8*>(&xjT[nb * 16 + ln][lq * 8]);
            bf8 bb1 = *reinterpret_cast<const bf8*>(&xjT[nb * 16 + ln][32 + lq * 8]);
            f4 gacc = {0.f, 0.f, 0.f, 0.f};
            gacc = __builtin_amdgcn_mfma_f32_16x16x32_bf16(a0, bb0, gacc, 0, 0, 0);
            gacc = __builtin_amdgcn_mfma_f32_16x16x32_bf16(a1, bb1, gacc, 0, 0, 0);
            const float xjv = XjL[nb * 16 + ln];
            #pragma unroll
            for (int r = 0; r < 4; ++r) {
                float e = fmaf(s11, gacc[r], fmaf(s1b2, XiV[r], fmaf(s2b1, xjv, c0)));
                rmin[r] = fminf(rmin[r], e);
                rmax[r] = fmaxf(rmax[r], e);
            }
        }
    }

    #pragma unroll
    for (int d = 1; d < 16; d <<= 1) {
        #pragma unroll
        for (int r = 0; r < 4; ++r) {
            rmin[r] = fminf(rmin[r], __shfl_xor(rmin[r], d, 64));
            rmax[r] = fmaxf(rmax[r], __shfl_xor(rmax[r], d, 64));
        }
    }
    float mn[4], inv[4];
    #pragma unroll
    for (int r = 0; r < 4; ++r) {
        mn[r]  = rmin[r];
        inv[r] = 1.f / (rmax[r] - rmin[r] + 1e-8f);
    }

    f4 macc[4];
    #pragma unroll
    for (int nb = 0; nb < 4; ++nb) macc[nb] = (f4){0.f, 0.f, 0.f, 0.f};
    float ps[4] = {0.f, 0.f, 0.f, 0.f};

    // ---------- pass 2: exp + P (bf16) + mixed MFMA ----------
    for (int j0 = 0; j0 < NT; j0 += TJ) {
        __syncthreads();   // protects xjT/xjn/P against previous iteration readers
        {
            const int row = tid >> 2, cs = (tid & 3) * 16;
            const bf8* src = reinterpret_cast<const bf8*>(xTb + (size_t)(j0 + row) * NCH + cs);
            bf8* dst = reinterpret_cast<bf8*>(&xjT[row][cs]);
            dst[0] = src[0];
            dst[1] = src[1];
        }
        {
            const int c = tid >> 2, js = (tid & 3) * 16;
            const float* s = &xb[(size_t)c * NT + j0 + js];
            float4 f0 = *reinterpret_cast<const float4*>(s);
            float4 f1 = *reinterpret_cast<const float4*>(s + 4);
            float4 fA = *reinterpret_cast<const float4*>(s + 8);
            float4 fB = *reinterpret_cast<const float4*>(s + 12);
            bf8 v0, v1;
            v0[0] = f2b(f0.x); v0[1] = f2b(f0.y); v0[2] = f2b(f0.z); v0[3] = f2b(f0.w);
            v0[4] = f2b(f1.x); v0[5] = f2b(f1.y); v0[6] = f2b(f1.z); v0[7] = f2b(f1.w);
            v1[0] = f2b(fA.x); v1[1] = f2b(fA.y); v1[2] = f2b(fA.z); v1[3] = f2b(fA.w);
            v1[4] = f2b(fB.x); v1[5] = f2b(fB.y); v1[6] = f2b(fB.z); v1[7] = f2b(fB.w);
            *reinterpret_cast<bf8*>(&xjn[c][js])     = v0;
            *reinterpret_cast<bf8*>(&xjn[c][js + 8]) = v1;
        }
        if (tid < 16)
            reinterpret_cast<float4*>(XjL)[tid] =
                reinterpret_cast<const float4*>(Xs + b * NT + j0)[tid];
        __syncthreads();

        bf8 a0 = *reinterpret_cast<const bf8*>(&xiT[wid * 16 + ln][lq * 8]);
        bf8 a1 = *reinterpret_cast<const bf8*>(&xiT[wid * 16 + ln][32 + lq * 8]);
        #pragma unroll
        for (int nb = 0; nb < 4; ++nb) {
            bf8 bb0 = *reinterpret_cast<const bf8*>(&xjT[nb * 16 + ln][lq * 8]);
            bf8 bb1 = *reinterpret_cast<const bf8*>(&xjT[nb * 16 + ln][32 + lq * 8]);
            f4 gacc = {0.f, 0.f, 0.f, 0.f};
            gacc = __builtin_amdgcn_mfma_f32_16x16x32_bf16(a0, bb0, gacc, 0, 0, 0);
            gacc = __builtin_amdgcn_mfma_f32_16x16x32_bf16(a1, bb1, gacc, 0, 0, 0);
            const float xjv = XjL[nb * 16 + ln];
            #pragma unroll
            for (int r = 0; r < 4; ++r) {
                float e = fmaf(s11, gacc[r], fmaf(s1b2, XiV[r], fmaf(s2b1, xjv, c0)));
                float p = __expf((e - mn[r]) * inv[r]);
                ps[r] += p;
                P[wid * 16 + lq * 4 + r][nb * 16 + ln] = f2b(p);
            }
        }
        __syncthreads();

        // mixed[c][i] += sum_j xjn[c][j] * P[i][j]
        bf8 ma0 = *reinterpret_cast<const bf8*>(&xjn[wid * 16 + ln][lq * 8]);
        bf8 ma1 = *reinterpret_cast<const bf8*>(&xjn[wid * 16 + ln][32 + lq * 8]);
        #pragma unroll
        for (int nb = 0; nb < 4; ++nb) {
            bf8 pb0 = *reinterpret_cast<const bf8*>(&P[nb * 16 + ln][lq * 8]);
            bf8 pb1 = *reinterpret_cast<const bf8*>(&P[nb * 16 + ln][32 + lq * 8]);
            macc[nb] = __builtin_amdgcn_mfma_f32_16x16x32_bf16(ma0, pb0, macc[nb], 0, 0, 0);
            macc[nb] = __builtin_amdgcn_mfma_f32_16x16x32_bf16(ma1, pb1, macc[nb], 0, 0, 0);
        }
    }

    // row sums -> LDS (each wave owns its 16 rows)
    #pragma unroll
    for (int d = 1; d < 16; d <<= 1)
        #pragma unroll
        for (int r = 0; r < 4; ++r) ps[r] += __shfl_xor(ps[r], d, 64);
    if (ln == 0) {
        #pragma unroll
        for (int r = 0; r < 4; ++r) rowSumL[wid * 16 + lq * 4 + r] = ps[r];
    }
    __syncthreads();

    // epilogue: out[b][c][i] = g * mixed[c][i] / rowSum[i] + x[b][c][i]
    #pragma unroll
    for (int nb = 0; nb < 4; ++nb) {
        const int i = i0 + nb * 16 + ln;
        const float rs = rowSumL[nb * 16 + ln];
        #pragma unroll
        for (int r = 0; r < 4; ++r) {
            const int c = wid * 16 + lq * 4 + r;
            const size_t off = ((size_t)b * NCH + c) * NT + i;
            out[off] = g * macc[nb][r] / rs + xb[(size_t)c * NT + i];
        }
    }
}

extern "C" void kernel_launch(void* const* d_in, const int* in_sizes, int n_in,
                              void* d_out, int out_size, void* d_ws, size_t ws_size,
                              hipStream_t stream) {
    const float* x     = (const float*)d_in[0];
    const float* w1    = (const float*)d_in[1];
    const float* b1    = (const float*)d_in[2];
    const float* w2    = (const float*)d_in[3];
    const float* b2    = (const float*)d_in[4];
    const float* gamma = (const float*)d_in[5];
    float* out = (float*)d_out;

    float* Xs = (float*)d_ws;                                  // 16*2048*4   = 128 KB
    short* xT = (short*)((char*)d_ws + (size_t)NB * NT * 4);   // 16*2048*64*2 = 4 MB

    hipLaunchKernelGGL(prep_k, dim3(NT / 64, NB), dim3(256), 0, stream, x, Xs, xT);
    hipLaunchKernelGGL(attn2_k, dim3(NT / TI, NB), dim3(256), 0, stream,
                       x, w1, b1, w2, b2, gamma, Xs, xT, out);
}

// Round 3
// 100.308 us; speedup vs baseline: 5.0446x; 1.1075x over previous
//
#include <hip/hip_runtime.h>

#define NB 16
#define NCH 64
#define NT 2048
#define TI 32
#define TJ 64
#define STR 72   // bf16 LDS row stride: 144 B rows -> bank step 4, conflict-free b128 frags

typedef __attribute__((ext_vector_type(8))) short bf8;   // 8 bf16 in 4 VGPRs
typedef __attribute__((ext_vector_type(4))) short bf4;   // 4 bf16
typedef __attribute__((ext_vector_type(4))) float f4;    // MFMA accumulator

static __device__ __forceinline__ short f2b(float f) {
    unsigned u = __float_as_uint(f);
    u += 0x7fffu + ((u >> 16) & 1u);
    return (short)(u >> 16);
}

// ---- prep: Xs[b][t] = sum_c x ; xT[b][t][c] bf16 ; xn[b][c][t] bf16 ----
__global__ __launch_bounds__(256)
void prep_k(const float* __restrict__ x, float* __restrict__ Xs,
            short* __restrict__ xT, short* __restrict__ xn) {
    __shared__ float T[NCH][65];
    const int b = blockIdx.y, t0 = blockIdx.x * 64;
    const int tid = threadIdx.x;
    const float* xb = x + (size_t)b * NCH * NT;

    const int tt = (tid & 15) * 4;
    #pragma unroll
    for (int co = 0; co < 4; ++co) {
        int c = co * 16 + (tid >> 4);
        float4 v = *reinterpret_cast<const float4*>(&xb[(size_t)c * NT + t0 + tt]);
        T[c][tt] = v.x; T[c][tt + 1] = v.y; T[c][tt + 2] = v.z; T[c][tt + 3] = v.w;
        bf4 w; w[0] = f2b(v.x); w[1] = f2b(v.y); w[2] = f2b(v.z); w[3] = f2b(v.w);
        *reinterpret_cast<bf4*>(&xn[((size_t)b * NCH + c) * NT + t0 + tt]) = w;
    }
    __syncthreads();
    if (tid < 64) {
        float s = 0.f;
        #pragma unroll
        for (int c = 0; c < NCH; ++c) s += T[c][tid];
        Xs[b * NT + t0 + tid] = s;
    }
    const int row = tid >> 2, cs = (tid & 3) * 16;
    bf8 v0, v1;
    #pragma unroll
    for (int u = 0; u < 8; ++u) v0[u] = f2b(T[cs + u][row]);
    #pragma unroll
    for (int u = 0; u < 8; ++u) v1[u] = f2b(T[cs + 8 + u][row]);
    short* dst = xT + ((size_t)b * NT + t0 + row) * NCH + cs;
    *reinterpret_cast<bf8*>(dst) = v0;
    *reinterpret_cast<bf8*>(dst + 8) = v1;
}

// ---- fused: energy(MFMA Gram) -> minmax -> softmax -> mixed(MFMA) -> out ----
__global__ __launch_bounds__(256)
void attn3_k(const float* __restrict__ x,
             const float* __restrict__ w1, const float* __restrict__ b1p,
             const float* __restrict__ w2, const float* __restrict__ b2p,
             const float* __restrict__ gp,
             const float* __restrict__ Xs, const short* __restrict__ xT,
             const short* __restrict__ xn,
             float* __restrict__ out) {
    __shared__ short xiT[TI][STR];   // xiT[i][c]
    __shared__ short xjT[TJ][STR];   // xjT[j][c]
    __shared__ short xjn[NCH][STR];  // xjn[c][j]
    __shared__ short P[TI][STR];     // P[i][j]
    __shared__ float XjL[TJ];
    __shared__ float redA[4][TI], redB[4][TI];
    __shared__ float rowMinL[TI], rowMaxL[TI], rowSumL[TI];

    const int b  = blockIdx.y;
    const int i0 = blockIdx.x * TI;
    const int tid  = threadIdx.x;
    const int wid  = tid >> 6;
    const int lane = tid & 63;
    const int lq   = lane >> 4;
    const int ln   = lane & 15;

    float s11 = 0.f, s1b2 = 0.f, s2b1 = 0.f, sbb = 0.f;
    #pragma unroll
    for (int f = 0; f < 8; ++f) {
        s11  += w1[f] * w2[f];
        s1b2 += w1[f] * b2p[f];
        s2b1 += b1p[f] * w2[f];
        sbb  += b1p[f] * b2p[f];
    }
    const float c0 = (float)NCH * sbb;
    const float g  = gp[0];

    const short* xTb = xT + (size_t)b * NT * NCH;
    const short* xnb = xn + (size_t)b * NCH * NT;
    const float* xb  = x + (size_t)b * NCH * NT;

    // stage xiT once: 32 rows x 64 ch (16 B / thread)
    {
        const int row = tid >> 3, cs = (tid & 7) * 8;
        *reinterpret_cast<bf8*>(&xiT[row][cs]) =
            *reinterpret_cast<const bf8*>(xTb + (size_t)(i0 + row) * NCH + cs);
    }

    float XiV[2][4];
    #pragma unroll
    for (int mb = 0; mb < 2; ++mb)
        #pragma unroll
        for (int r = 0; r < 4; ++r)
            XiV[mb][r] = Xs[b * NT + i0 + mb * 16 + lq * 4 + r];

    float rmin[2][4], rmax[2][4];
    #pragma unroll
    for (int mb = 0; mb < 2; ++mb)
        #pragma unroll
        for (int r = 0; r < 4; ++r) { rmin[mb][r] = 3.0e38f; rmax[mb][r] = -3.0e38f; }

    // ---------- pass 1: row min/max ----------
    for (int j0 = 0; j0 < NT; j0 += TJ) {
        __syncthreads();
        {
            const int row = tid >> 2, cs = (tid & 3) * 16;
            const bf8* src = reinterpret_cast<const bf8*>(xTb + (size_t)(j0 + row) * NCH + cs);
            bf8* dst = reinterpret_cast<bf8*>(&xjT[row][cs]);
            dst[0] = src[0];
            dst[1] = src[1];
        }
        if (tid < 16)
            reinterpret_cast<float4*>(XjL)[tid] =
                reinterpret_cast<const float4*>(Xs + b * NT + j0)[tid];
        __syncthreads();

        bf8 b0 = *reinterpret_cast<const bf8*>(&xjT[wid * 16 + ln][lq * 8]);
        bf8 b1 = *reinterpret_cast<const bf8*>(&xjT[wid * 16 + ln][32 + lq * 8]);
        const float xjv = XjL[wid * 16 + ln];
        #pragma unroll
        for (int mb = 0; mb < 2; ++mb) {
            bf8 a0 = *reinterpret_cast<const bf8*>(&xiT[mb * 16 + ln][lq * 8]);
            bf8 a1 = *reinterpret_cast<const bf8*>(&xiT[mb * 16 + ln][32 + lq * 8]);
            f4 gacc = {0.f, 0.f, 0.f, 0.f};
            gacc = __builtin_amdgcn_mfma_f32_16x16x32_bf16(a0, b0, gacc, 0, 0, 0);
            gacc = __builtin_amdgcn_mfma_f32_16x16x32_bf16(a1, b1, gacc, 0, 0, 0);
            #pragma unroll
            for (int r = 0; r < 4; ++r) {
                float e = fmaf(s11, gacc[r], fmaf(s1b2, XiV[mb][r], fmaf(s2b1, xjv, c0)));
                rmin[mb][r] = fminf(rmin[mb][r], e);
                rmax[mb][r] = fmaxf(rmax[mb][r], e);
            }
        }
    }

    // reduce over ln lanes (keep lq)
    #pragma unroll
    for (int d = 1; d < 16; d <<= 1)
        #pragma unroll
        for (int mb = 0; mb < 2; ++mb)
            #pragma unroll
            for (int r = 0; r < 4; ++r) {
                rmin[mb][r] = fminf(rmin[mb][r], __shfl_xor(rmin[mb][r], d, 64));
                rmax[mb][r] = fmaxf(rmax[mb][r], __shfl_xor(rmax[mb][r], d, 64));
            }
    if (ln == 0)
        #pragma unroll
        for (int mb = 0; mb < 2; ++mb)
            #pragma unroll
            for (int r = 0; r < 4; ++r) {
                redA[wid][mb * 16 + lq * 4 + r] = rmin[mb][r];
                redB[wid][mb * 16 + lq * 4 + r] = rmax[mb][r];
            }
    __syncthreads();
    if (tid < TI) {
        float a = redA[0][tid], bb = redB[0][tid];
        #pragma unroll
        for (int w = 1; w < 4; ++w) {
            a  = fminf(a, redA[w][tid]);
            bb = fmaxf(bb, redB[w][tid]);
        }
        rowMinL[tid] = a;
        rowMaxL[tid] = bb;
    }
    __syncthreads();

    float mn[2][4], inv[2][4];
    #pragma unroll
    for (int mb = 0; mb < 2; ++mb)
        #pragma unroll
        for (int r = 0; r < 4; ++r) {
            const int i = mb * 16 + lq * 4 + r;
            mn[mb][r]  = rowMinL[i];
            inv[mb][r] = 1.f / (rowMaxL[i] - rowMinL[i] + 1e-8f);
        }

    f4 macc[2];
    macc[0] = (f4){0.f, 0.f, 0.f, 0.f};
    macc[1] = (f4){0.f, 0.f, 0.f, 0.f};
    float ps[2][4] = {};

    // ---------- pass 2: exp + P (bf16) + mixed MFMA ----------
    for (int j0 = 0; j0 < NT; j0 += TJ) {
        __syncthreads();
        {
            const int row = tid >> 2, cs = (tid & 3) * 16;
            const bf8* src = reinterpret_cast<const bf8*>(xTb + (size_t)(j0 + row) * NCH + cs);
            bf8* dst = reinterpret_cast<bf8*>(&xjT[row][cs]);
            dst[0] = src[0];
            dst[1] = src[1];
            const bf8* src2 = reinterpret_cast<const bf8*>(xnb + (size_t)row * NT + j0 + (tid & 3) * 16);
            bf8* dst2 = reinterpret_cast<bf8*>(&xjn[row][(tid & 3) * 16]);
            dst2[0] = src2[0];
            dst2[1] = src2[1];
        }
        if (tid < 16)
            reinterpret_cast<float4*>(XjL)[tid] =
                reinterpret_cast<const float4*>(Xs + b * NT + j0)[tid];
        __syncthreads();

        bf8 b0 = *reinterpret_cast<const bf8*>(&xjT[wid * 16 + ln][lq * 8]);
        bf8 b1 = *reinterpret_cast<const bf8*>(&xjT[wid * 16 + ln][32 + lq * 8]);
        const float xjv = XjL[wid * 16 + ln];
        #pragma unroll
        for (int mb = 0; mb < 2; ++mb) {
            bf8 a0 = *reinterpret_cast<const bf8*>(&xiT[mb * 16 + ln][lq * 8]);
            bf8 a1 = *reinterpret_cast<const bf8*>(&xiT[mb * 16 + ln][32 + lq * 8]);
            f4 gacc = {0.f, 0.f, 0.f, 0.f};
            gacc = __builtin_amdgcn_mfma_f32_16x16x32_bf16(a0, b0, gacc, 0, 0, 0);
            gacc = __builtin_amdgcn_mfma_f32_16x16x32_bf16(a1, b1, gacc, 0, 0, 0);
            #pragma unroll
            for (int r = 0; r < 4; ++r) {
                float e = fmaf(s11, gacc[r], fmaf(s1b2, XiV[mb][r], fmaf(s2b1, xjv, c0)));
                float p = __expf((e - mn[mb][r]) * inv[mb][r]);
                ps[mb][r] += p;
                P[mb * 16 + lq * 4 + r][wid * 16 + ln] = f2b(p);
            }
        }
        __syncthreads();

        // mixed[c][i] += sum_j xjn[c][j] * P[i][j]
        bf8 ma0 = *reinterpret_cast<const bf8*>(&xjn[wid * 16 + ln][lq * 8]);
        bf8 ma1 = *reinterpret_cast<const bf8*>(&xjn[wid * 16 + ln][32 + lq * 8]);
        #pragma unroll
        for (int nb = 0; nb < 2; ++nb) {
            bf8 pb0 = *reinterpret_cast<const bf8*>(&P[nb * 16 + ln][lq * 8]);
            bf8 pb1 = *reinterpret_cast<const bf8*>(&P[nb * 16 + ln][32 + lq * 8]);
            macc[nb] = __builtin_amdgcn_mfma_f32_16x16x32_bf16(ma0, pb0, macc[nb], 0, 0, 0);
            macc[nb] = __builtin_amdgcn_mfma_f32_16x16x32_bf16(ma1, pb1, macc[nb], 0, 0, 0);
        }
    }

    // row sums
    #pragma unroll
    for (int d = 1; d < 16; d <<= 1)
        #pragma unroll
        for (int mb = 0; mb < 2; ++mb)
            #pragma unroll
            for (int r = 0; r < 4; ++r)
                ps[mb][r] += __shfl_xor(ps[mb][r], d, 64);
    if (ln == 0)
        #pragma unroll
        for (int mb = 0; mb < 2; ++mb)
            #pragma unroll
            for (int r = 0; r < 4; ++r)
                redA[wid][mb * 16 + lq * 4 + r] = ps[mb][r];
    __syncthreads();
    if (tid < TI) {
        float s = 0.f;
        #pragma unroll
        for (int w = 0; w < 4; ++w) s += redA[w][tid];
        rowSumL[tid] = s;
    }
    __syncthreads();

    // epilogue
    #pragma unroll
    for (int nb = 0; nb < 2; ++nb) {
        const int i = i0 + nb * 16 + ln;
        const float rs = rowSumL[nb * 16 + ln];
        #pragma unroll
        for (int r = 0; r < 4; ++r) {
            const int c = wid * 16 + lq * 4 + r;
            const size_t off = ((size_t)b * NCH + c) * NT + i;
            out[off] = g * macc[nb][r] / rs + xb[(size_t)c * NT + i];
        }
    }
}

extern "C" void kernel_launch(void* const* d_in, const int* in_sizes, int n_in,
                              void* d_out, int out_size, void* d_ws, size_t ws_size,
                              hipStream_t stream) {
    const float* x     = (const float*)d_in[0];
    const float* w1    = (const float*)d_in[1];
    const float* b1    = (const float*)d_in[2];
    const float* w2    = (const float*)d_in[3];
    const float* b2    = (const float*)d_in[4];
    const float* gamma = (const float*)d_in[5];
    float* out = (float*)d_out;

    float* Xs = (float*)d_ws;                                        // 128 KB
    short* xT = (short*)((char*)d_ws + (size_t)NB * NT * 4);         // 4 MB
    short* xn = (short*)((char*)d_ws + (size_t)NB * NT * 4
                         + (size_t)NB * NT * NCH * 2);               // 4 MB

    hipLaunchKernelGGL(prep_k, dim3(NT / 64, NB), dim3(256), 0, stream, x, Xs, xT, xn);
    hipLaunchKernelGGL(attn3_k, dim3(NT / TI, NB), dim3(256), 0, stream,
                       x, w1, b1, w2, b2, gamma, Xs, xT, xn, out);
}